// Round 8
// baseline (224.928 us; speedup 1.0000x reference)
//
#include <hip/hip_runtime.h>
#include <hip/hip_bf16.h>

typedef __attribute__((ext_vector_type(4))) float f32x4;
typedef __attribute__((ext_vector_type(8))) short bf16x8;
typedef __attribute__((ext_vector_type(4))) short bf16x4;

static constexpr int S = 2048;
static constexpr int D = 64;
static constexpr int QB = 64;    // Q rows per block (16 per wave)
static constexpr int KVB = 64;   // KV rows per tile
static constexpr float SCALE = 0.125f;           // 1/sqrt(64)
static constexpr float LOG2E = 1.44269504088896340736f;
static constexpr size_t ARR = (size_t)32 * 32 * 4096;   // shorts per ws array
static constexpr size_t WS_NEED = 3 * ARR * sizeof(unsigned short); // 25,165,824 B

__device__ __forceinline__ unsigned short f2bf(float f) {
    unsigned int u = __builtin_bit_cast(unsigned int, f);
    u += 0x7fffu + ((u >> 16) & 1u);             // round-to-nearest-even
    return (unsigned short)(u >> 16);
}
__device__ __forceinline__ float bf2f(unsigned short h) {
    unsigned int u = ((unsigned int)h) << 16;
    return __builtin_bit_cast(float, u);
}
// XOR swizzle at 16B granularity: index in shorts, rows of 64 shorts (128B)
__device__ __forceinline__ int swz(int r, int c) {
    return r * 64 + (c ^ ((r & 7) << 3));
}
__device__ __forceinline__ void gload16(const void* g, void* l) {
    __builtin_amdgcn_global_load_lds(
        (const __attribute__((address_space(1))) unsigned int*)g,
        (__attribute__((address_space(3))) unsigned int*)l, 16, 0, 0);
}

// ---------------- prepass: x(f32) -> Khi/Klo (row-major) + Vt (transposed), bf16,
// tile-contiguous [pair*32+t][64][64]. Run once per call; ~40 MB traffic.
__global__ __launch_bounds__(256) void prep_convert(const float* __restrict__ x,
        unsigned short* __restrict__ Khi_g, unsigned short* __restrict__ Klo_g,
        unsigned short* __restrict__ Vt_g) {
    __shared__ unsigned short Lhi[64 * 65];
    const int tid = threadIdx.x;
    const int blk = blockIdx.x;          // pr*32 + t  (x tile base == blk*4096)
    const int r  = tid >> 2;
    const int c0 = (tid & 3) << 4;
    const float* rp = x + (size_t)blk * 4096 + r * 64 + c0;
    unsigned short hi[16], lo[16];
    #pragma unroll
    for (int i = 0; i < 16; i += 4) {
        float4 f = *(const float4*)(rp + i);
        float fv[4] = {f.x, f.y, f.z, f.w};
        #pragma unroll
        for (int k = 0; k < 4; ++k) {
            hi[i + k] = f2bf(fv[k]);
            lo[i + k] = f2bf(fv[k] - bf2f(hi[i + k]));
        }
    }
    bf16x8 h0, h1, l0, l1;
    #pragma unroll
    for (int i = 0; i < 8; ++i) {
        h0[i] = (short)hi[i]; h1[i] = (short)hi[i + 8];
        l0[i] = (short)lo[i]; l1[i] = (short)lo[i + 8];
    }
    const size_t ob = (size_t)blk * 4096 + r * 64 + c0;
    *(bf16x8*)&Khi_g[ob] = h0;  *(bf16x8*)&Khi_g[ob + 8] = h1;
    *(bf16x8*)&Klo_g[ob] = l0;  *(bf16x8*)&Klo_g[ob + 8] = l1;
    #pragma unroll
    for (int i = 0; i < 16; ++i) Lhi[r * 65 + c0 + i] = hi[i];
    __syncthreads();
    // transpose within the 64x64 tile: this thread emits row d=r of Vt, cols c0..c0+15
    unsigned short tv[16];
    #pragma unroll
    for (int i = 0; i < 16; ++i) tv[i] = Lhi[(c0 + i) * 65 + r];
    bf16x8 t0, t1;
    #pragma unroll
    for (int i = 0; i < 8; ++i) { t0[i] = (short)tv[i]; t1[i] = (short)tv[i + 8]; }
    *(bf16x8*)&Vt_g[ob] = t0;  *(bf16x8*)&Vt_g[ob + 8] = t1;
}

// ---------------- main attention kernel: 2-phase pipeline, double-buffered LDS,
// ONE barrier per KV tile (T3 minimum recipe). Pl is per-wave (no barrier needed).
__global__ __launch_bounds__(256, 2) void attn_fwd2(
        const unsigned short* __restrict__ Khi_g,
        const unsigned short* __restrict__ Klo_g,
        const unsigned short* __restrict__ Vt_g,
        float* __restrict__ out) {
    __shared__ __align__(16) unsigned short KhiB[2][KVB * D];
    __shared__ __align__(16) unsigned short KloB[2][KVB * D];
    __shared__ __align__(16) unsigned short VtB[2][D * KVB];
    __shared__ __align__(16) unsigned short Pl[4 * 16 * KVB];

    const int tid  = threadIdx.x;
    const int lane = tid & 63;
    const int wave = tid >> 6;
    const int l15  = lane & 15;
    const int g    = lane >> 4;
    const int pr = blockIdx.x & 31;
    const int qt = blockIdx.x >> 5;

    // ---- Q fragments straight from pre-converted arrays (no VALU convert)
    const size_t qbase = ((size_t)pr * 32 + qt) * 4096 + (size_t)(wave * 16 + l15) * 64 + g * 8;
    bf16x8 a_hi[2], a_lo[2];
    a_hi[0] = *(const bf16x8*)&Khi_g[qbase];
    a_hi[1] = *(const bf16x8*)&Khi_g[qbase + 32];
    a_lo[0] = *(const bf16x8*)&Klo_g[qbase];
    a_lo[1] = *(const bf16x8*)&Klo_g[qbase + 32];

    f32x4 O[4];
    f32x4 zero4 = {0.f, 0.f, 0.f, 0.f};
    #pragma unroll
    for (int n = 0; n < 4; ++n) O[n] = zero4;
    float m_run[4] = {-INFINITY, -INFINITY, -INFINITY, -INFINITY};
    float l_run[4] = {0.f, 0.f, 0.f, 0.f};

    // staging source offset (bytes): LDS slot (r=wave*8+(l>>3), cl=(l&7)*8) <-
    // global short r*64 + (cl ^ ((r&7)<<3))  [pre-swizzled source, linear LDS dest]
    const int go = wave * 1024 + (lane >> 3) * 128 + (((lane & 7) ^ (lane >> 3)) << 4);
    const size_t prbase = (size_t)pr * 32 * 8192;   // byte base of this pair

    // issue staging of one tile into buffer b
    auto stage = [&](int t, int b) {
        const size_t tb = prbase + (size_t)t * 8192;
        const char* kh = (const char*)Khi_g + tb;
        const char* kl = (const char*)Klo_g + tb;
        const char* vt = (const char*)Vt_g + tb;
        char* KhiL = (char*)KhiB[b] + wave * 1024;
        char* KloL = (char*)KloB[b] + wave * 1024;
        char* VtL  = (char*)VtB[b]  + wave * 1024;
        gload16(kh + go,        KhiL);
        gload16(kh + go + 4096, KhiL + 4096);
        gload16(kl + go,        KloL);
        gload16(kl + go + 4096, KloL + 4096);
        gload16(vt + go,        VtL);
        gload16(vt + go + 4096, VtL + 4096);
    };

    stage(0, 0);
    __syncthreads();   // vmcnt(0) drained by compiler before barrier: buf0 ready

    for (int t = 0; t < 32; ++t) {
        const int cur = t & 1;
        if (t + 1 < 32) stage(t + 1, cur ^ 1);   // in flight during compute of t

        const unsigned short* Khi = KhiB[cur];
        const unsigned short* Klo = KloB[cur];
        const unsigned short* Vt  = VtB[cur];

        // ---- S = Q K^T with hi/lo compensation (f32 accum)
        f32x4 st[4];
        #pragma unroll
        for (int n = 0; n < 4; ++n) {
            f32x4 acc = zero4;
            #pragma unroll
            for (int c = 0; c < 2; ++c) {
                int krow = n * 16 + l15;
                int col = c * 32 + g * 8;
                bf16x8 bh = *(const bf16x8*)(&Khi[swz(krow, col)]);
                bf16x8 bl = *(const bf16x8*)(&Klo[swz(krow, col)]);
                acc = __builtin_amdgcn_mfma_f32_16x16x32_bf16(a_lo[c], bh, acc, 0, 0, 0);
                acc = __builtin_amdgcn_mfma_f32_16x16x32_bf16(a_hi[c], bl, acc, 0, 0, 0);
                acc = __builtin_amdgcn_mfma_f32_16x16x32_bf16(a_hi[c], bh, acc, 0, 0, 0);
            }
            st[n] = acc;
        }

        // ---- online softmax; rows of this wave's tile: g*4 + j
        #pragma unroll
        for (int j = 0; j < 4; ++j) {
            float tt[4];
            #pragma unroll
            for (int n = 0; n < 4; ++n) tt[n] = st[n][j] * SCALE;
            float mx = fmaxf(fmaxf(tt[0], tt[1]), fmaxf(tt[2], tt[3]));
            #pragma unroll
            for (int w = 1; w <= 8; w <<= 1) mx = fmaxf(mx, __shfl_xor(mx, w, 64));
            float M = fmaxf(m_run[j], mx);
            float f = exp2f((m_run[j] - M) * LOG2E);
            m_run[j] = M;
            float p[4], sum = 0.f;
            #pragma unroll
            for (int n = 0; n < 4; ++n) {
                p[n] = exp2f((tt[n] - M) * LOG2E);
                sum += p[n];
            }
            #pragma unroll
            for (int w = 1; w <= 8; w <<= 1) sum += __shfl_xor(sum, w, 64);
            l_run[j] = l_run[j] * f + sum;
            #pragma unroll
            for (int n = 0; n < 4; ++n) O[n][j] *= f;
            int r = g * 4 + j;
            #pragma unroll
            for (int n = 0; n < 4; ++n)
                Pl[wave * 1024 + r * 64 + ((n * 16 + l15) ^ ((r & 7) << 3))] = f2bf(p[n]);
        }
        // NO barrier: Pl region is per-wave private; lgkmcnt dependency orders it.

        // ---- O += P V
        #pragma unroll
        for (int c = 0; c < 2; ++c) {
            int pcol = c * 32 + g * 8;
            bf16x8 pa = *(const bf16x8*)(&Pl[wave * 1024 + swz(l15, pcol)]);
            #pragma unroll
            for (int n = 0; n < 4; ++n) {
                bf16x8 vb = *(const bf16x8*)(&Vt[swz(n * 16 + l15, pcol)]);
                O[n] = __builtin_amdgcn_mfma_f32_16x16x32_bf16(pa, vb, O[n], 0, 0, 0);
            }
        }

        if (t + 1 < 32) __syncthreads();  // drains staging of t+1; gates reuse of buf[t&1]
    }

    // ---- epilogue
    const int hh = pr >> 1, bb = pr & 1;
    #pragma unroll
    for (int j = 0; j < 4; ++j) {
        float inv = 1.0f / l_run[j];
        int s = qt * QB + wave * 16 + g * 4 + j;
        float* op = out + (((size_t)(hh * S + s)) * 2 + bb) * 64;
        #pragma unroll
        for (int n = 0; n < 4; ++n) op[n * 16 + l15] = O[n][j] * inv;
    }
}

// ---------------- legacy fallback (round-6 verified kernel) for small ws_size
__global__ __launch_bounds__(256, 2) void attn_fwd(const float* __restrict__ x,
                                                   float* __restrict__ out) {
    __shared__ __align__(16) unsigned short Khi[KVB * D];
    __shared__ __align__(16) unsigned short Klo[KVB * D];
    __shared__ __align__(16) unsigned short Vt[D * KVB];
    __shared__ __align__(16) unsigned short Pl[4 * 16 * KVB];

    const int tid  = threadIdx.x;
    const int lane = tid & 63;
    const int wave = tid >> 6;
    const int l15  = lane & 15;
    const int g    = lane >> 4;
    const int pr = blockIdx.x & 31;
    const int qt = blockIdx.x >> 5;
    const float* __restrict__ base = x + (size_t)pr * (S * D);

    bf16x8 a_hi[2], a_lo[2];
    const int qrow = qt * QB + wave * 16 + l15;
    #pragma unroll
    for (int c = 0; c < 2; ++c) {
        const float* qp = base + qrow * D + c * 32 + g * 8;
        float4 q0 = *(const float4*)(qp);
        float4 q1 = *(const float4*)(qp + 4);
        float qv[8] = {q0.x, q0.y, q0.z, q0.w, q1.x, q1.y, q1.z, q1.w};
        bf16x8 hv, lv;
        #pragma unroll
        for (int i = 0; i < 8; ++i) {
            unsigned short hb = f2bf(qv[i]);
            hv[i] = (short)hb;
            lv[i] = (short)f2bf(qv[i] - bf2f(hb));
        }
        a_hi[c] = hv;
        a_lo[c] = lv;
    }

    f32x4 O[4];
    f32x4 zero4 = {0.f, 0.f, 0.f, 0.f};
    #pragma unroll
    for (int n = 0; n < 4; ++n) O[n] = zero4;
    float m_run[4] = {-INFINITY, -INFINITY, -INFINITY, -INFINITY};
    float l_run[4] = {0.f, 0.f, 0.f, 0.f};

    for (int kv = 0; kv < S; kv += KVB) {
        #pragma unroll
        for (int it = 0; it < 4; ++it) {
            int o = it * 1024 + tid * 4;
            int r = o >> 6;
            int c = o & 63;
            float4 v = *(const float4*)(base + (size_t)(kv + r) * D + c);
            float vv[4] = {v.x, v.y, v.z, v.w};
            unsigned short hb[4];
            bf16x4 hvv, lvv;
            #pragma unroll
            for (int i = 0; i < 4; ++i) {
                hb[i] = f2bf(vv[i]);
                hvv[i] = (short)hb[i];
                lvv[i] = (short)f2bf(vv[i] - bf2f(hb[i]));
            }
            int idx = swz(r, c);
            *(bf16x4*)(&Khi[idx]) = hvv;
            *(bf16x4*)(&Klo[idx]) = lvv;
            #pragma unroll
            for (int i = 0; i < 4; ++i) Vt[swz(c + i, r)] = hb[i];
        }
        __syncthreads();

        f32x4 st[4];
        #pragma unroll
        for (int n = 0; n < 4; ++n) {
            f32x4 acc = zero4;
            #pragma unroll
            for (int c = 0; c < 2; ++c) {
                int krow = n * 16 + l15;
                int col = c * 32 + g * 8;
                bf16x8 bh = *(const bf16x8*)(&Khi[swz(krow, col)]);
                bf16x8 bl = *(const bf16x8*)(&Klo[swz(krow, col)]);
                acc = __builtin_amdgcn_mfma_f32_16x16x32_bf16(a_lo[c], bh, acc, 0, 0, 0);
                acc = __builtin_amdgcn_mfma_f32_16x16x32_bf16(a_hi[c], bl, acc, 0, 0, 0);
                acc = __builtin_amdgcn_mfma_f32_16x16x32_bf16(a_hi[c], bh, acc, 0, 0, 0);
            }
            st[n] = acc;
        }

        #pragma unroll
        for (int j = 0; j < 4; ++j) {
            float tt[4];
            #pragma unroll
            for (int n = 0; n < 4; ++n) tt[n] = st[n][j] * SCALE;
            float mx = fmaxf(fmaxf(tt[0], tt[1]), fmaxf(tt[2], tt[3]));
            #pragma unroll
            for (int w = 1; w <= 8; w <<= 1) mx = fmaxf(mx, __shfl_xor(mx, w, 64));
            float M = fmaxf(m_run[j], mx);
            float f = exp2f((m_run[j] - M) * LOG2E);
            m_run[j] = M;
            float p[4], sum = 0.f;
            #pragma unroll
            for (int n = 0; n < 4; ++n) {
                p[n] = exp2f((tt[n] - M) * LOG2E);
                sum += p[n];
            }
            #pragma unroll
            for (int w = 1; w <= 8; w <<= 1) sum += __shfl_xor(sum, w, 64);
            l_run[j] = l_run[j] * f + sum;
            #pragma unroll
            for (int n = 0; n < 4; ++n) O[n][j] *= f;
            int r = g * 4 + j;
            #pragma unroll
            for (int n = 0; n < 4; ++n)
                Pl[wave * 1024 + r * 64 + ((n * 16 + l15) ^ ((r & 7) << 3))] = f2bf(p[n]);
        }
        __syncthreads();

        #pragma unroll
        for (int c = 0; c < 2; ++c) {
            int pcol = c * 32 + g * 8;
            bf16x8 pa = *(const bf16x8*)(&Pl[wave * 1024 + swz(l15, pcol)]);
            #pragma unroll
            for (int n = 0; n < 4; ++n) {
                bf16x8 vb = *(const bf16x8*)(&Vt[swz(n * 16 + l15, pcol)]);
                O[n] = __builtin_amdgcn_mfma_f32_16x16x32_bf16(pa, vb, O[n], 0, 0, 0);
            }
        }
        __syncthreads();
    }

    const int hh = pr >> 1, bb = pr & 1;
    #pragma unroll
    for (int j = 0; j < 4; ++j) {
        float inv = 1.0f / l_run[j];
        int s = qt * QB + wave * 16 + g * 4 + j;
        float* op = out + (((size_t)(hh * S + s)) * 2 + bb) * 64;
        #pragma unroll
        for (int n = 0; n < 4; ++n) op[n * 16 + l15] = O[n][j] * inv;
    }
}

extern "C" void kernel_launch(void* const* d_in, const int* in_sizes, int n_in,
                              void* d_out, int out_size, void* d_ws, size_t ws_size,
                              hipStream_t stream) {
    (void)in_sizes; (void)n_in; (void)out_size;
    const float* x = (const float*)d_in[0];
    float* out = (float*)d_out;
    if (ws_size >= WS_NEED) {
        unsigned short* Khi_g = (unsigned short*)d_ws;
        unsigned short* Klo_g = Khi_g + ARR;
        unsigned short* Vt_g  = Klo_g + ARR;
        prep_convert<<<dim3(1024), dim3(256), 0, stream>>>(x, Khi_g, Klo_g, Vt_g);
        attn_fwd2<<<dim3(1024), dim3(256), 0, stream>>>(Khi_g, Klo_g, Vt_g, out);
    } else {
        attn_fwd<<<dim3(1024), dim3(256), 0, stream>>>(x, out);
    }
}

// Round 15
// 185.644 us; speedup vs baseline: 1.2116x; 1.2116x over previous
//
#include <hip/hip_runtime.h>
#include <hip/hip_bf16.h>

typedef __attribute__((ext_vector_type(4))) float f32x4;
typedef __attribute__((ext_vector_type(8))) short bf16x8;
typedef __attribute__((ext_vector_type(4))) short bf16x4;

static constexpr int S = 2048;
static constexpr int D = 64;
static constexpr int QB = 64;    // Q rows per block (16 per wave)
static constexpr int KVB = 64;   // KV rows per tile
static constexpr float SCALE = 0.125f;           // 1/sqrt(64)
static constexpr float LOG2E = 1.44269504088896340736f;
static constexpr size_t ARR = (size_t)32 * 32 * 4096;   // shorts per ws array
static constexpr size_t WS_NEED = 2 * ARR * sizeof(unsigned short); // 16,777,216 B

__device__ __forceinline__ unsigned short f2bf(float f) {
    unsigned int u = __builtin_bit_cast(unsigned int, f);
    u += 0x7fffu + ((u >> 16) & 1u);             // round-to-nearest-even
    return (unsigned short)(u >> 16);
}
__device__ __forceinline__ float bf2f(unsigned short h) {
    unsigned int u = ((unsigned int)h) << 16;
    return __builtin_bit_cast(float, u);
}
// XOR swizzle at 16B granularity: index in shorts, rows of 64 shorts (128B)
__device__ __forceinline__ int swz(int r, int c) {
    return r * 64 + (c ^ ((r & 7) << 3));
}
__device__ __forceinline__ void gload16(const void* g, void* l) {
    __builtin_amdgcn_global_load_lds(
        (const __attribute__((address_space(1))) unsigned int*)g,
        (__attribute__((address_space(3))) unsigned int*)l, 16, 0, 0);
}

// ---------------- prepass: x(f32) -> K (row-major bf16) + Vt (transposed bf16),
// tile-contiguous [pair*32+t][64][64]. Run once per call.
__global__ __launch_bounds__(256) void prep_convert(const float* __restrict__ x,
        unsigned short* __restrict__ Khi_g, unsigned short* __restrict__ Vt_g) {
    __shared__ unsigned short Lhi[64 * 65];
    const int tid = threadIdx.x;
    const int blk = blockIdx.x;          // pr*32 + t  (x tile base == blk*4096)
    const int r  = tid >> 2;
    const int c0 = (tid & 3) << 4;
    const float* rp = x + (size_t)blk * 4096 + r * 64 + c0;
    unsigned short hi[16];
    #pragma unroll
    for (int i = 0; i < 16; i += 4) {
        float4 f = *(const float4*)(rp + i);
        float fv[4] = {f.x, f.y, f.z, f.w};
        #pragma unroll
        for (int k = 0; k < 4; ++k) hi[i + k] = f2bf(fv[k]);
    }
    bf16x8 h0, h1;
    #pragma unroll
    for (int i = 0; i < 8; ++i) { h0[i] = (short)hi[i]; h1[i] = (short)hi[i + 8]; }
    const size_t ob = (size_t)blk * 4096 + r * 64 + c0;
    *(bf16x8*)&Khi_g[ob] = h0;  *(bf16x8*)&Khi_g[ob + 8] = h1;
    #pragma unroll
    for (int i = 0; i < 16; ++i) Lhi[r * 65 + c0 + i] = hi[i];
    __syncthreads();
    // transpose within the 64x64 tile: this thread emits row d=r of Vt, cols c0..c0+15
    unsigned short tv[16];
    #pragma unroll
    for (int i = 0; i < 16; ++i) tv[i] = Lhi[(c0 + i) * 65 + r];
    bf16x8 t0, t1;
    #pragma unroll
    for (int i = 0; i < 8; ++i) { t0[i] = (short)tv[i]; t1[i] = (short)tv[i + 8]; }
    *(bf16x8*)&Vt_g[ob] = t0;  *(bf16x8*)&Vt_g[ob + 8] = t1;
}

// ---------------- main attention kernel: 2-phase pipeline, double-buffered LDS
// (40 KB -> 4 blocks/CU), ONE barrier per KV tile. Pl per-wave (no barrier).
__global__ __launch_bounds__(256, 4) void attn_fwd2(
        const unsigned short* __restrict__ Khi_g,
        const unsigned short* __restrict__ Vt_g,
        float* __restrict__ out) {
    __shared__ __align__(16) unsigned short KhiB[2][KVB * D];
    __shared__ __align__(16) unsigned short VtB[2][D * KVB];
    __shared__ __align__(16) unsigned short Pl[4 * 16 * KVB];

    const int tid  = threadIdx.x;
    const int lane = tid & 63;
    const int wave = tid >> 6;
    const int l15  = lane & 15;
    const int g    = lane >> 4;
    const int pr = blockIdx.x & 31;
    const int qt = blockIdx.x >> 5;

    // ---- Q fragments straight from pre-converted array (no VALU convert)
    const size_t qbase = ((size_t)pr * 32 + qt) * 4096 + (size_t)(wave * 16 + l15) * 64 + g * 8;
    bf16x8 a_hi[2];
    a_hi[0] = *(const bf16x8*)&Khi_g[qbase];
    a_hi[1] = *(const bf16x8*)&Khi_g[qbase + 32];

    f32x4 O[4];
    f32x4 zero4 = {0.f, 0.f, 0.f, 0.f};
    #pragma unroll
    for (int n = 0; n < 4; ++n) O[n] = zero4;
    float m_run[4] = {-INFINITY, -INFINITY, -INFINITY, -INFINITY};
    float l_run[4] = {0.f, 0.f, 0.f, 0.f};

    // staging source offset (bytes): LDS slot (r=wave*8+(l>>3), cl=(l&7)*8) <-
    // global short r*64 + (cl ^ ((r&7)<<3))  [pre-swizzled source, linear LDS dest]
    const int go = wave * 1024 + (lane >> 3) * 128 + (((lane & 7) ^ (lane >> 3)) << 4);
    const size_t prbase = (size_t)pr * 32 * 8192;   // byte base of this pair

    // issue staging of one tile into buffer b
    auto stage = [&](int t, int b) {
        const size_t tb = prbase + (size_t)t * 8192;
        const char* kh = (const char*)Khi_g + tb;
        const char* vt = (const char*)Vt_g + tb;
        char* KhiL = (char*)KhiB[b] + wave * 1024;
        char* VtL  = (char*)VtB[b]  + wave * 1024;
        gload16(kh + go,        KhiL);
        gload16(kh + go + 4096, KhiL + 4096);
        gload16(vt + go,        VtL);
        gload16(vt + go + 4096, VtL + 4096);
    };

    stage(0, 0);
    __syncthreads();   // vmcnt(0) drained by compiler before barrier: buf0 ready

    for (int t = 0; t < 32; ++t) {
        const int cur = t & 1;
        if (t + 1 < 32) stage(t + 1, cur ^ 1);   // in flight during compute of t

        const unsigned short* Khi = KhiB[cur];
        const unsigned short* Vt  = VtB[cur];

        // ---- S = Q K^T (bf16, f32 accum)
        f32x4 st[4];
        #pragma unroll
        for (int n = 0; n < 4; ++n) {
            f32x4 acc = zero4;
            #pragma unroll
            for (int c = 0; c < 2; ++c) {
                int krow = n * 16 + l15;
                int col = c * 32 + g * 8;
                bf16x8 bh = *(const bf16x8*)(&Khi[swz(krow, col)]);
                acc = __builtin_amdgcn_mfma_f32_16x16x32_bf16(a_hi[c], bh, acc, 0, 0, 0);
            }
            st[n] = acc;
        }

        // ---- online softmax; rows of this wave's tile: g*4 + j
        #pragma unroll
        for (int j = 0; j < 4; ++j) {
            float tt[4];
            #pragma unroll
            for (int n = 0; n < 4; ++n) tt[n] = st[n][j] * SCALE;
            float mx = fmaxf(fmaxf(tt[0], tt[1]), fmaxf(tt[2], tt[3]));
            #pragma unroll
            for (int w = 1; w <= 8; w <<= 1) mx = fmaxf(mx, __shfl_xor(mx, w, 64));
            float M = fmaxf(m_run[j], mx);
            float f = exp2f((m_run[j] - M) * LOG2E);
            m_run[j] = M;
            float p[4], sum = 0.f;
            #pragma unroll
            for (int n = 0; n < 4; ++n) {
                p[n] = exp2f((tt[n] - M) * LOG2E);
                sum += p[n];
            }
            #pragma unroll
            for (int w = 1; w <= 8; w <<= 1) sum += __shfl_xor(sum, w, 64);
            l_run[j] = l_run[j] * f + sum;
            #pragma unroll
            for (int n = 0; n < 4; ++n) O[n][j] *= f;
            int r = g * 4 + j;
            #pragma unroll
            for (int n = 0; n < 4; ++n)
                Pl[wave * 1024 + r * 64 + ((n * 16 + l15) ^ ((r & 7) << 3))] = f2bf(p[n]);
        }
        // NO barrier: Pl region is per-wave private; lgkmcnt dependency orders it.

        // ---- O += P V
        #pragma unroll
        for (int c = 0; c < 2; ++c) {
            int pcol = c * 32 + g * 8;
            bf16x8 pa = *(const bf16x8*)(&Pl[wave * 1024 + swz(l15, pcol)]);
            #pragma unroll
            for (int n = 0; n < 4; ++n) {
                bf16x8 vb = *(const bf16x8*)(&Vt[swz(n * 16 + l15, pcol)]);
                O[n] = __builtin_amdgcn_mfma_f32_16x16x32_bf16(pa, vb, O[n], 0, 0, 0);
            }
        }

        if (t + 1 < 32) __syncthreads();  // drains staging of t+1; gates reuse of buf[t&1]
    }

    // ---- epilogue
    const int hh = pr >> 1, bb = pr & 1;
    #pragma unroll
    for (int j = 0; j < 4; ++j) {
        float inv = 1.0f / l_run[j];
        int s = qt * QB + wave * 16 + g * 4 + j;
        float* op = out + (((size_t)(hh * S + s)) * 2 + bb) * 64;
        #pragma unroll
        for (int n = 0; n < 4; ++n) op[n * 16 + l15] = O[n][j] * inv;
    }
}

// ---------------- legacy fallback (round-6 verified kernel) for small ws_size
__global__ __launch_bounds__(256, 2) void attn_fwd(const float* __restrict__ x,
                                                   float* __restrict__ out) {
    __shared__ __align__(16) unsigned short Khi[KVB * D];
    __shared__ __align__(16) unsigned short Klo[KVB * D];
    __shared__ __align__(16) unsigned short Vt[D * KVB];
    __shared__ __align__(16) unsigned short Pl[4 * 16 * KVB];

    const int tid  = threadIdx.x;
    const int lane = tid & 63;
    const int wave = tid >> 6;
    const int l15  = lane & 15;
    const int g    = lane >> 4;
    const int pr = blockIdx.x & 31;
    const int qt = blockIdx.x >> 5;
    const float* __restrict__ base = x + (size_t)pr * (S * D);

    bf16x8 a_hi[2], a_lo[2];
    const int qrow = qt * QB + wave * 16 + l15;
    #pragma unroll
    for (int c = 0; c < 2; ++c) {
        const float* qp = base + qrow * D + c * 32 + g * 8;
        float4 q0 = *(const float4*)(qp);
        float4 q1 = *(const float4*)(qp + 4);
        float qv[8] = {q0.x, q0.y, q0.z, q0.w, q1.x, q1.y, q1.z, q1.w};
        bf16x8 hv, lv;
        #pragma unroll
        for (int i = 0; i < 8; ++i) {
            unsigned short hb = f2bf(qv[i]);
            hv[i] = (short)hb;
            lv[i] = (short)f2bf(qv[i] - bf2f(hb));
        }
        a_hi[c] = hv;
        a_lo[c] = lv;
    }

    f32x4 O[4];
    f32x4 zero4 = {0.f, 0.f, 0.f, 0.f};
    #pragma unroll
    for (int n = 0; n < 4; ++n) O[n] = zero4;
    float m_run[4] = {-INFINITY, -INFINITY, -INFINITY, -INFINITY};
    float l_run[4] = {0.f, 0.f, 0.f, 0.f};

    for (int kv = 0; kv < S; kv += KVB) {
        #pragma unroll
        for (int it = 0; it < 4; ++it) {
            int o = it * 1024 + tid * 4;
            int r = o >> 6;
            int c = o & 63;
            float4 v = *(const float4*)(base + (size_t)(kv + r) * D + c);
            float vv[4] = {v.x, v.y, v.z, v.w};
            unsigned short hb[4];
            bf16x4 hvv, lvv;
            #pragma unroll
            for (int i = 0; i < 4; ++i) {
                hb[i] = f2bf(vv[i]);
                hvv[i] = (short)hb[i];
                lvv[i] = (short)f2bf(vv[i] - bf2f(hb[i]));
            }
            int idx = swz(r, c);
            *(bf16x4*)(&Khi[idx]) = hvv;
            *(bf16x4*)(&Klo[idx]) = lvv;
            #pragma unroll
            for (int i = 0; i < 4; ++i) Vt[swz(c + i, r)] = hb[i];
        }
        __syncthreads();

        f32x4 st[4];
        #pragma unroll
        for (int n = 0; n < 4; ++n) {
            f32x4 acc = zero4;
            #pragma unroll
            for (int c = 0; c < 2; ++c) {
                int krow = n * 16 + l15;
                int col = c * 32 + g * 8;
                bf16x8 bh = *(const bf16x8*)(&Khi[swz(krow, col)]);
                bf16x8 bl = *(const bf16x8*)(&Klo[swz(krow, col)]);
                acc = __builtin_amdgcn_mfma_f32_16x16x32_bf16(a_lo[c], bh, acc, 0, 0, 0);
                acc = __builtin_amdgcn_mfma_f32_16x16x32_bf16(a_hi[c], bl, acc, 0, 0, 0);
                acc = __builtin_amdgcn_mfma_f32_16x16x32_bf16(a_hi[c], bh, acc, 0, 0, 0);
            }
            st[n] = acc;
        }

        #pragma unroll
        for (int j = 0; j < 4; ++j) {
            float tt[4];
            #pragma unroll
            for (int n = 0; n < 4; ++n) tt[n] = st[n][j] * SCALE;
            float mx = fmaxf(fmaxf(tt[0], tt[1]), fmaxf(tt[2], tt[3]));
            #pragma unroll
            for (int w = 1; w <= 8; w <<= 1) mx = fmaxf(mx, __shfl_xor(mx, w, 64));
            float M = fmaxf(m_run[j], mx);
            float f = exp2f((m_run[j] - M) * LOG2E);
            m_run[j] = M;
            float p[4], sum = 0.f;
            #pragma unroll
            for (int n = 0; n < 4; ++n) {
                p[n] = exp2f((tt[n] - M) * LOG2E);
                sum += p[n];
            }
            #pragma unroll
            for (int w = 1; w <= 8; w <<= 1) sum += __shfl_xor(sum, w, 64);
            l_run[j] = l_run[j] * f + sum;
            #pragma unroll
            for (int n = 0; n < 4; ++n) O[n][j] *= f;
            int r = g * 4 + j;
            #pragma unroll
            for (int n = 0; n < 4; ++n)
                Pl[wave * 1024 + r * 64 + ((n * 16 + l15) ^ ((r & 7) << 3))] = f2bf(p[n]);
        }
        __syncthreads();

        #pragma unroll
        for (int c = 0; c < 2; ++c) {
            int pcol = c * 32 + g * 8;
            bf16x8 pa = *(const bf16x8*)(&Pl[wave * 1024 + swz(l15, pcol)]);
            #pragma unroll
            for (int n = 0; n < 4; ++n) {
                bf16x8 vb = *(const bf16x8*)(&Vt[swz(n * 16 + l15, pcol)]);
                O[n] = __builtin_amdgcn_mfma_f32_16x16x32_bf16(pa, vb, O[n], 0, 0, 0);
            }
        }
        __syncthreads();
    }

    const int hh = pr >> 1, bb = pr & 1;
    #pragma unroll
    for (int j = 0; j < 4; ++j) {
        float inv = 1.0f / l_run[j];
        int s = qt * QB + wave * 16 + g * 4 + j;
        float* op = out + (((size_t)(hh * S + s)) * 2 + bb) * 64;
        #pragma unroll
        for (int n = 0; n < 4; ++n) op[n * 16 + l15] = O[n][j] * inv;
    }
}

extern "C" void kernel_launch(void* const* d_in, const int* in_sizes, int n_in,
                              void* d_out, int out_size, void* d_ws, size_t ws_size,
                              hipStream_t stream) {
    (void)in_sizes; (void)n_in; (void)out_size;
    const float* x = (const float*)d_in[0];
    float* out = (float*)d_out;
    if (ws_size >= WS_NEED) {
        unsigned short* Khi_g = (unsigned short*)d_ws;
        unsigned short* Vt_g  = Khi_g + ARR;
        prep_convert<<<dim3(1024), dim3(256), 0, stream>>>(x, Khi_g, Vt_g);
        attn_fwd2<<<dim3(1024), dim3(256), 0, stream>>>(Khi_g, Vt_g, out);
    } else {
        attn_fwd<<<dim3(1024), dim3(256), 0, stream>>>(x, out);
    }
}

// Round 16
// 174.248 us; speedup vs baseline: 1.2908x; 1.0654x over previous
//
#include <hip/hip_runtime.h>
#include <hip/hip_bf16.h>

typedef __attribute__((ext_vector_type(4))) float f32x4;
typedef __attribute__((ext_vector_type(8))) short bf16x8;
typedef __attribute__((ext_vector_type(4))) short bf16x4;

static constexpr int S = 2048;
static constexpr int D = 64;
static constexpr int KVB = 64;   // KV rows per tile
static constexpr float SCALE = 0.125f;           // 1/sqrt(64)
static constexpr float LOG2E = 1.44269504088896340736f;
static constexpr size_t ARR = (size_t)32 * 32 * 4096;   // shorts per ws array
static constexpr size_t WS_NEED = 2 * ARR * sizeof(unsigned short); // 16,777,216 B

__device__ __forceinline__ unsigned short f2bf(float f) {
    unsigned int u = __builtin_bit_cast(unsigned int, f);
    u += 0x7fffu + ((u >> 16) & 1u);             // round-to-nearest-even
    return (unsigned short)(u >> 16);
}
__device__ __forceinline__ float bf2f(unsigned short h) {
    unsigned int u = ((unsigned int)h) << 16;
    return __builtin_bit_cast(float, u);
}
// XOR swizzle at 16B granularity: index in shorts, rows of 64 shorts (128B)
__device__ __forceinline__ int swz(int r, int c) {
    return r * 64 + (c ^ ((r & 7) << 3));
}
__device__ __forceinline__ void gload16(const void* g, void* l) {
    __builtin_amdgcn_global_load_lds(
        (const __attribute__((address_space(1))) unsigned int*)g,
        (__attribute__((address_space(3))) unsigned int*)l, 16, 0, 0);
}

// ---------------- prepass: x(f32) -> K (row-major bf16) + Vt (transposed bf16),
// tile-contiguous [pair*32+t][64][64]. Run once per call.
__global__ __launch_bounds__(256) void prep_convert(const float* __restrict__ x,
        unsigned short* __restrict__ Khi_g, unsigned short* __restrict__ Vt_g) {
    __shared__ unsigned short Lhi[64 * 65];
    const int tid = threadIdx.x;
    const int blk = blockIdx.x;          // pr*32 + t  (x tile base == blk*4096)
    const int r  = tid >> 2;
    const int c0 = (tid & 3) << 4;
    const float* rp = x + (size_t)blk * 4096 + r * 64 + c0;
    unsigned short hi[16];
    #pragma unroll
    for (int i = 0; i < 16; i += 4) {
        float4 f = *(const float4*)(rp + i);
        float fv[4] = {f.x, f.y, f.z, f.w};
        #pragma unroll
        for (int k = 0; k < 4; ++k) hi[i + k] = f2bf(fv[k]);
    }
    bf16x8 h0, h1;
    #pragma unroll
    for (int i = 0; i < 8; ++i) { h0[i] = (short)hi[i]; h1[i] = (short)hi[i + 8]; }
    const size_t ob = (size_t)blk * 4096 + r * 64 + c0;
    *(bf16x8*)&Khi_g[ob] = h0;  *(bf16x8*)&Khi_g[ob + 8] = h1;
    #pragma unroll
    for (int i = 0; i < 16; ++i) Lhi[r * 65 + c0 + i] = hi[i];
    __syncthreads();
    // transpose within the 64x64 tile: this thread emits row d=r of Vt, cols c0..c0+15
    unsigned short tv[16];
    #pragma unroll
    for (int i = 0; i < 16; ++i) tv[i] = Lhi[(c0 + i) * 65 + r];
    bf16x8 t0, t1;
    #pragma unroll
    for (int i = 0; i < 8; ++i) { t0[i] = (short)tv[i]; t1[i] = (short)tv[i + 8]; }
    *(bf16x8*)&Vt_g[ob] = t0;  *(bf16x8*)&Vt_g[ob + 8] = t1;
}

// ---------------- main attention kernel: 8 waves, QB=128 q-rows/block, grid 512
// (= exactly 2 blocks/CU, no tail), double-buffered LDS (48 KB), ONE barrier/tile.
__global__ __launch_bounds__(512, 4) void attn_fwd2(
        const unsigned short* __restrict__ Khi_g,
        const unsigned short* __restrict__ Vt_g,
        float* __restrict__ out) {
    __shared__ __align__(16) unsigned short KhiB[2][KVB * D];
    __shared__ __align__(16) unsigned short VtB[2][D * KVB];
    __shared__ __align__(16) unsigned short Pl[8 * 16 * KVB];

    const int tid  = threadIdx.x;
    const int lane = tid & 63;
    const int wave = tid >> 6;          // 0..7
    const int l15  = lane & 15;
    const int g    = lane >> 4;
    const int pr = blockIdx.x & 31;     // pair
    const int qt = blockIdx.x >> 5;     // 0..15, 128 q-rows each

    // ---- Q fragments from pre-converted array; q row = qt*128 + wave*16 + l15
    const int tq = qt * 2 + (wave >> 2);            // q's 64-row tile index
    const int rin = (wave & 3) * 16 + l15;          // row within that tile
    const size_t qbase = ((size_t)pr * 32 + tq) * 4096 + (size_t)rin * 64 + g * 8;
    bf16x8 a_hi[2];
    a_hi[0] = *(const bf16x8*)&Khi_g[qbase];
    a_hi[1] = *(const bf16x8*)&Khi_g[qbase + 32];

    f32x4 O[4];
    f32x4 zero4 = {0.f, 0.f, 0.f, 0.f};
    #pragma unroll
    for (int n = 0; n < 4; ++n) O[n] = zero4;
    float m_run[4] = {-INFINITY, -INFINITY, -INFINITY, -INFINITY};
    float l_run[4] = {0.f, 0.f, 0.f, 0.f};

    // staging source offset (bytes): LDS slot (r=wave*8+(l>>3), cl=(l&7)*8) <-
    // global short r*64 + (cl ^ ((r&7)<<3))  [pre-swizzled source, linear LDS dest]
    const int go = wave * 1024 + (lane >> 3) * 128 + (((lane & 7) ^ (lane >> 3)) << 4);
    const size_t prbase = (size_t)pr * 32 * 8192;   // byte base of this pair

    // issue staging of one tile into buffer b (each of 8 waves covers 1 KB/array)
    auto stage = [&](int t, int b) {
        const size_t tb = prbase + (size_t)t * 8192;
        gload16((const char*)Khi_g + tb + go, (char*)KhiB[b] + wave * 1024);
        gload16((const char*)Vt_g  + tb + go, (char*)VtB[b]  + wave * 1024);
    };

    stage(0, 0);
    __syncthreads();   // vmcnt(0) drained by compiler before barrier: buf0 ready

    for (int t = 0; t < 32; ++t) {
        const int cur = t & 1;
        if (t + 1 < 32) stage(t + 1, cur ^ 1);   // in flight during compute of t

        const unsigned short* Khi = KhiB[cur];
        const unsigned short* Vt  = VtB[cur];

        // ---- S = Q K^T (bf16, f32 accum)
        f32x4 st[4];
        #pragma unroll
        for (int n = 0; n < 4; ++n) {
            f32x4 acc = zero4;
            #pragma unroll
            for (int c = 0; c < 2; ++c) {
                int krow = n * 16 + l15;
                int col = c * 32 + g * 8;
                bf16x8 bh = *(const bf16x8*)(&Khi[swz(krow, col)]);
                acc = __builtin_amdgcn_mfma_f32_16x16x32_bf16(a_hi[c], bh, acc, 0, 0, 0);
            }
            st[n] = acc;
        }

        // ---- online softmax; rows of this wave's tile: g*4 + j
        #pragma unroll
        for (int j = 0; j < 4; ++j) {
            float tt[4];
            #pragma unroll
            for (int n = 0; n < 4; ++n) tt[n] = st[n][j] * SCALE;
            float mx = fmaxf(fmaxf(tt[0], tt[1]), fmaxf(tt[2], tt[3]));
            #pragma unroll
            for (int w = 1; w <= 8; w <<= 1) mx = fmaxf(mx, __shfl_xor(mx, w, 64));
            float M = fmaxf(m_run[j], mx);
            float f = exp2f((m_run[j] - M) * LOG2E);
            m_run[j] = M;
            float p[4], sum = 0.f;
            #pragma unroll
            for (int n = 0; n < 4; ++n) {
                p[n] = exp2f((tt[n] - M) * LOG2E);
                sum += p[n];
            }
            #pragma unroll
            for (int w = 1; w <= 8; w <<= 1) sum += __shfl_xor(sum, w, 64);
            l_run[j] = l_run[j] * f + sum;
            #pragma unroll
            for (int n = 0; n < 4; ++n) O[n][j] *= f;
            int r = g * 4 + j;
            #pragma unroll
            for (int n = 0; n < 4; ++n)
                Pl[wave * 1024 + r * 64 + ((n * 16 + l15) ^ ((r & 7) << 3))] = f2bf(p[n]);
        }
        // NO barrier: Pl region is per-wave private; lgkmcnt dependency orders it.

        // ---- O += P V
        #pragma unroll
        for (int c = 0; c < 2; ++c) {
            int pcol = c * 32 + g * 8;
            bf16x8 pa = *(const bf16x8*)(&Pl[wave * 1024 + swz(l15, pcol)]);
            #pragma unroll
            for (int n = 0; n < 4; ++n) {
                bf16x8 vb = *(const bf16x8*)(&Vt[swz(n * 16 + l15, pcol)]);
                O[n] = __builtin_amdgcn_mfma_f32_16x16x32_bf16(pa, vb, O[n], 0, 0, 0);
            }
        }

        if (t + 1 < 32) __syncthreads();  // drains staging of t+1; gates reuse of buf[t&1]
    }

    // ---- epilogue
    const int hh = pr >> 1, bb = pr & 1;
    #pragma unroll
    for (int j = 0; j < 4; ++j) {
        float inv = 1.0f / l_run[j];
        int s = qt * 128 + wave * 16 + g * 4 + j;
        float* op = out + (((size_t)(hh * S + s)) * 2 + bb) * 64;
        #pragma unroll
        for (int n = 0; n < 4; ++n) op[n * 16 + l15] = O[n][j] * inv;
    }
}

// ---------------- legacy fallback (round-6 verified kernel) for small ws_size
__global__ __launch_bounds__(256, 2) void attn_fwd(const float* __restrict__ x,
                                                   float* __restrict__ out) {
    __shared__ __align__(16) unsigned short Khi[KVB * D];
    __shared__ __align__(16) unsigned short Klo[KVB * D];
    __shared__ __align__(16) unsigned short Vt[D * KVB];
    __shared__ __align__(16) unsigned short Pl[4 * 16 * KVB];

    const int tid  = threadIdx.x;
    const int lane = tid & 63;
    const int wave = tid >> 6;
    const int l15  = lane & 15;
    const int g    = lane >> 4;
    const int pr = blockIdx.x & 31;
    const int qt = blockIdx.x >> 5;
    const float* __restrict__ base = x + (size_t)pr * (S * D);

    bf16x8 a_hi[2], a_lo[2];
    const int qrow = qt * 64 + wave * 16 + l15;
    #pragma unroll
    for (int c = 0; c < 2; ++c) {
        const float* qp = base + qrow * D + c * 32 + g * 8;
        float4 q0 = *(const float4*)(qp);
        float4 q1 = *(const float4*)(qp + 4);
        float qv[8] = {q0.x, q0.y, q0.z, q0.w, q1.x, q1.y, q1.z, q1.w};
        bf16x8 hv, lv;
        #pragma unroll
        for (int i = 0; i < 8; ++i) {
            unsigned short hb = f2bf(qv[i]);
            hv[i] = (short)hb;
            lv[i] = (short)f2bf(qv[i] - bf2f(hb));
        }
        a_hi[c] = hv;
        a_lo[c] = lv;
    }

    f32x4 O[4];
    f32x4 zero4 = {0.f, 0.f, 0.f, 0.f};
    #pragma unroll
    for (int n = 0; n < 4; ++n) O[n] = zero4;
    float m_run[4] = {-INFINITY, -INFINITY, -INFINITY, -INFINITY};
    float l_run[4] = {0.f, 0.f, 0.f, 0.f};

    for (int kv = 0; kv < S; kv += KVB) {
        #pragma unroll
        for (int it = 0; it < 4; ++it) {
            int o = it * 1024 + tid * 4;
            int r = o >> 6;
            int c = o & 63;
            float4 v = *(const float4*)(base + (size_t)(kv + r) * D + c);
            float vv[4] = {v.x, v.y, v.z, v.w};
            unsigned short hb[4];
            bf16x4 hvv, lvv;
            #pragma unroll
            for (int i = 0; i < 4; ++i) {
                hb[i] = f2bf(vv[i]);
                hvv[i] = (short)hb[i];
                lvv[i] = (short)f2bf(vv[i] - bf2f(hb[i]));
            }
            int idx = swz(r, c);
            *(bf16x4*)(&Khi[idx]) = hvv;
            *(bf16x4*)(&Klo[idx]) = lvv;
            #pragma unroll
            for (int i = 0; i < 4; ++i) Vt[swz(c + i, r)] = hb[i];
        }
        __syncthreads();

        f32x4 st[4];
        #pragma unroll
        for (int n = 0; n < 4; ++n) {
            f32x4 acc = zero4;
            #pragma unroll
            for (int c = 0; c < 2; ++c) {
                int krow = n * 16 + l15;
                int col = c * 32 + g * 8;
                bf16x8 bh = *(const bf16x8*)(&Khi[swz(krow, col)]);
                bf16x8 bl = *(const bf16x8*)(&Klo[swz(krow, col)]);
                acc = __builtin_amdgcn_mfma_f32_16x16x32_bf16(a_lo[c], bh, acc, 0, 0, 0);
                acc = __builtin_amdgcn_mfma_f32_16x16x32_bf16(a_hi[c], bl, acc, 0, 0, 0);
                acc = __builtin_amdgcn_mfma_f32_16x16x32_bf16(a_hi[c], bh, acc, 0, 0, 0);
            }
            st[n] = acc;
        }

        #pragma unroll
        for (int j = 0; j < 4; ++j) {
            float tt[4];
            #pragma unroll
            for (int n = 0; n < 4; ++n) tt[n] = st[n][j] * SCALE;
            float mx = fmaxf(fmaxf(tt[0], tt[1]), fmaxf(tt[2], tt[3]));
            #pragma unroll
            for (int w = 1; w <= 8; w <<= 1) mx = fmaxf(mx, __shfl_xor(mx, w, 64));
            float M = fmaxf(m_run[j], mx);
            float f = exp2f((m_run[j] - M) * LOG2E);
            m_run[j] = M;
            float p[4], sum = 0.f;
            #pragma unroll
            for (int n = 0; n < 4; ++n) {
                p[n] = exp2f((tt[n] - M) * LOG2E);
                sum += p[n];
            }
            #pragma unroll
            for (int w = 1; w <= 8; w <<= 1) sum += __shfl_xor(sum, w, 64);
            l_run[j] = l_run[j] * f + sum;
            #pragma unroll
            for (int n = 0; n < 4; ++n) O[n][j] *= f;
            int r = g * 4 + j;
            #pragma unroll
            for (int n = 0; n < 4; ++n)
                Pl[wave * 1024 + r * 64 + ((n * 16 + l15) ^ ((r & 7) << 3))] = f2bf(p[n]);
        }
        __syncthreads();

        #pragma unroll
        for (int c = 0; c < 2; ++c) {
            int pcol = c * 32 + g * 8;
            bf16x8 pa = *(const bf16x8*)(&Pl[wave * 1024 + swz(l15, pcol)]);
            #pragma unroll
            for (int n = 0; n < 4; ++n) {
                bf16x8 vb = *(const bf16x8*)(&Vt[swz(n * 16 + l15, pcol)]);
                O[n] = __builtin_amdgcn_mfma_f32_16x16x32_bf16(pa, vb, O[n], 0, 0, 0);
            }
        }
        __syncthreads();
    }

    const int hh = pr >> 1, bb = pr & 1;
    #pragma unroll
    for (int j = 0; j < 4; ++j) {
        float inv = 1.0f / l_run[j];
        int s = qt * 64 + wave * 16 + g * 4 + j;
        float* op = out + (((size_t)(hh * S + s)) * 2 + bb) * 64;
        #pragma unroll
        for (int n = 0; n < 4; ++n) op[n * 16 + l15] = O[n][j] * inv;
    }
}

extern "C" void kernel_launch(void* const* d_in, const int* in_sizes, int n_in,
                              void* d_out, int out_size, void* d_ws, size_t ws_size,
                              hipStream_t stream) {
    (void)in_sizes; (void)n_in; (void)out_size;
    const float* x = (const float*)d_in[0];
    float* out = (float*)d_out;
    if (ws_size >= WS_NEED) {
        unsigned short* Khi_g = (unsigned short*)d_ws;
        unsigned short* Vt_g  = Khi_g + ARR;
        prep_convert<<<dim3(1024), dim3(256), 0, stream>>>(x, Khi_g, Vt_g);
        attn_fwd2<<<dim3(512), dim3(512), 0, stream>>>(Khi_g, Vt_g, out);
    } else {
        attn_fwd<<<dim3(1024), dim3(256), 0, stream>>>(x, out);
    }
}

// Round 17
// 147.429 us; speedup vs baseline: 1.5257x; 1.1819x over previous
//
#include <hip/hip_runtime.h>
#include <hip/hip_bf16.h>

typedef __attribute__((ext_vector_type(4))) float f32x4;
typedef __attribute__((ext_vector_type(8))) short bf16x8;
typedef __attribute__((ext_vector_type(4))) short bf16x4;

static constexpr int S = 2048;
static constexpr int D = 64;
static constexpr int KVB = 64;   // KV rows per tile
static constexpr float SCALE = 0.125f;           // 1/sqrt(64)
static constexpr float LOG2E = 1.44269504088896340736f;
static constexpr size_t ARR = (size_t)32 * 32 * 4096;   // shorts per ws array
static constexpr size_t WS_NEED = 2 * ARR * sizeof(unsigned short); // 16,777,216 B

__device__ __forceinline__ unsigned short f2bf(float f) {
    unsigned int u = __builtin_bit_cast(unsigned int, f);
    u += 0x7fffu + ((u >> 16) & 1u);             // round-to-nearest-even
    return (unsigned short)(u >> 16);
}
__device__ __forceinline__ float bf2f(unsigned short h) {
    unsigned int u = ((unsigned int)h) << 16;
    return __builtin_bit_cast(float, u);
}
// XOR swizzle at 16B granularity: index in shorts, rows of 64 shorts (128B)
__device__ __forceinline__ int swz(int r, int c) {
    return r * 64 + (c ^ ((r & 7) << 3));
}
__device__ __forceinline__ void gload16(const void* g, void* l) {
    __builtin_amdgcn_global_load_lds(
        (const __attribute__((address_space(1))) unsigned int*)g,
        (__attribute__((address_space(3))) unsigned int*)l, 16, 0, 0);
}

// ---------------- prepass: x(f32) -> K (row-major bf16) + Vt (transposed bf16),
// tile-contiguous [pair*32+t][64][64]. Run once per call.
__global__ __launch_bounds__(256) void prep_convert(const float* __restrict__ x,
        unsigned short* __restrict__ Khi_g, unsigned short* __restrict__ Vt_g) {
    __shared__ unsigned short Lhi[64 * 65];
    const int tid = threadIdx.x;
    const int blk = blockIdx.x;          // pr*32 + t  (x tile base == blk*4096)
    const int r  = tid >> 2;
    const int c0 = (tid & 3) << 4;
    const float* rp = x + (size_t)blk * 4096 + r * 64 + c0;
    unsigned short hi[16];
    #pragma unroll
    for (int i = 0; i < 16; i += 4) {
        float4 f = *(const float4*)(rp + i);
        float fv[4] = {f.x, f.y, f.z, f.w};
        #pragma unroll
        for (int k = 0; k < 4; ++k) hi[i + k] = f2bf(fv[k]);
    }
    bf16x8 h0, h1;
    #pragma unroll
    for (int i = 0; i < 8; ++i) { h0[i] = (short)hi[i]; h1[i] = (short)hi[i + 8]; }
    const size_t ob = (size_t)blk * 4096 + r * 64 + c0;
    *(bf16x8*)&Khi_g[ob] = h0;  *(bf16x8*)&Khi_g[ob + 8] = h1;
    #pragma unroll
    for (int i = 0; i < 16; ++i) Lhi[r * 65 + c0 + i] = hi[i];
    __syncthreads();
    // transpose within the 64x64 tile: this thread emits row d=r of Vt, cols c0..c0+15
    unsigned short tv[16];
    #pragma unroll
    for (int i = 0; i < 16; ++i) tv[i] = Lhi[(c0 + i) * 65 + r];
    bf16x8 t0, t1;
    #pragma unroll
    for (int i = 0; i < 8; ++i) { t0[i] = (short)tv[i]; t1[i] = (short)tv[i + 8]; }
    *(bf16x8*)&Vt_g[ob] = t0;  *(bf16x8*)&Vt_g[ob + 8] = t1;
}

// ---------------- main attention kernel: 8 waves, QB=128, grid 512, swapped QK^T
// (mfma(K,Q) -> P lane-local per q-row): 2-shfl softmax, b64 P-writes.
__global__ __launch_bounds__(512, 4) void attn_fwd2(
        const unsigned short* __restrict__ Khi_g,
        const unsigned short* __restrict__ Vt_g,
        float* __restrict__ out) {
    __shared__ __align__(16) unsigned short KhiB[2][KVB * D];
    __shared__ __align__(16) unsigned short VtB[2][D * KVB];
    __shared__ __align__(16) unsigned short Pl[8 * 16 * KVB];

    const int tid  = threadIdx.x;
    const int lane = tid & 63;
    const int wave = tid >> 6;          // 0..7
    const int l15  = lane & 15;
    const int g    = lane >> 4;
    const int pr = blockIdx.x & 31;     // pair
    const int qt = blockIdx.x >> 5;     // 0..15, 128 q-rows each

    // ---- Q fragments; q row = qt*128 + wave*16 + l15 (used as MFMA B operand too)
    const int tq = qt * 2 + (wave >> 2);            // q's 64-row tile index
    const int rin = (wave & 3) * 16 + l15;          // row within that tile
    const size_t qbase = ((size_t)pr * 32 + tq) * 4096 + (size_t)rin * 64 + g * 8;
    bf16x8 a_hi[2];
    a_hi[0] = *(const bf16x8*)&Khi_g[qbase];
    a_hi[1] = *(const bf16x8*)&Khi_g[qbase + 32];

    f32x4 O[4];
    f32x4 zero4 = {0.f, 0.f, 0.f, 0.f};
    #pragma unroll
    for (int n = 0; n < 4; ++n) O[n] = zero4;
    float m_run = -INFINITY;   // running max of q-row l15 (all 4 g copies identical)
    float l_run = 0.f;         // running denom of q-row l15

    // staging source offset (bytes): LDS slot (r=wave*8+(l>>3), cl=(l&7)*8) <-
    // global short r*64 + (cl ^ ((r&7)<<3))  [pre-swizzled source, linear LDS dest]
    const int go = wave * 1024 + (lane >> 3) * 128 + (((lane & 7) ^ (lane >> 3)) << 4);
    const size_t prbase = (size_t)pr * 32 * 8192;   // byte base of this pair

    auto stage = [&](int t, int b) {
        const size_t tb = prbase + (size_t)t * 8192;
        gload16((const char*)Khi_g + tb + go, (char*)KhiB[b] + wave * 1024);
        gload16((const char*)Vt_g  + tb + go, (char*)VtB[b]  + wave * 1024);
    };

    stage(0, 0);
    __syncthreads();   // buf0 ready

    for (int t = 0; t < 32; ++t) {
        const int cur = t & 1;
        if (t + 1 < 32) stage(t + 1, cur ^ 1);   // in flight during compute of t

        const unsigned short* Khi = KhiB[cur];
        const unsigned short* Vt  = VtB[cur];

        // ---- St = K Q^T : St[k=kb*16+g*4+j][q=l15] (A=K from LDS, B=Q regs)
        f32x4 stw[4];
        #pragma unroll
        for (int kb = 0; kb < 4; ++kb) {
            f32x4 acc = zero4;
            #pragma unroll
            for (int c = 0; c < 2; ++c) {
                bf16x8 ka = *(const bf16x8*)(&Khi[swz(kb * 16 + l15, c * 32 + g * 8)]);
                acc = __builtin_amdgcn_mfma_f32_16x16x32_bf16(ka, a_hi[c], acc, 0, 0, 0);
            }
            stw[kb] = acc;
        }

        // ---- softmax for q-row l15 (16 lane-local values), 2-shfl reduce over g
        float tt[16];
        #pragma unroll
        for (int kb = 0; kb < 4; ++kb)
            #pragma unroll
            for (int j = 0; j < 4; ++j) tt[kb * 4 + j] = stw[kb][j] * SCALE;
        float mx = tt[0];
        #pragma unroll
        for (int i = 1; i < 16; ++i) mx = fmaxf(mx, tt[i]);
        mx = fmaxf(mx, __shfl_xor(mx, 16, 64));
        mx = fmaxf(mx, __shfl_xor(mx, 32, 64));
        float M = fmaxf(m_run, mx);
        float f = exp2f((m_run - M) * LOG2E);
        m_run = M;
        float sum = 0.f;
        #pragma unroll
        for (int i = 0; i < 16; ++i) {
            tt[i] = exp2f((tt[i] - M) * LOG2E);
            sum += tt[i];
        }
        sum += __shfl_xor(sum, 16, 64);
        sum += __shfl_xor(sum, 32, 64);
        l_run = l_run * f + sum;

        // ---- write P row l15, k=kb*16+g*4..+3 as one b64 per kb (4 DS writes)
        #pragma unroll
        for (int kb = 0; kb < 4; ++kb) {
            bf16x4 pk;
            #pragma unroll
            for (int j = 0; j < 4; ++j) pk[j] = (short)f2bf(tt[kb * 4 + j]);
            *(bf16x4*)(&Pl[wave * 1024 + swz(l15, kb * 16 + g * 4)]) = pk;
        }

        // ---- rescale O rows (g*4+j) by that row's f (shfl from row-owner lane)
        #pragma unroll
        for (int j = 0; j < 4; ++j) {
            float fr = __shfl(f, (lane & 48) | (g * 4 + j), 64);
            #pragma unroll
            for (int n = 0; n < 4; ++n) O[n][j] *= fr;
        }

        // ---- O += P V   (A = P rows from Pl, B = V columns from Vt rows)
        #pragma unroll
        for (int c = 0; c < 2; ++c) {
            int pcol = c * 32 + g * 8;
            bf16x8 pa = *(const bf16x8*)(&Pl[wave * 1024 + swz(l15, pcol)]);
            #pragma unroll
            for (int n = 0; n < 4; ++n) {
                bf16x8 vb = *(const bf16x8*)(&Vt[swz(n * 16 + l15, pcol)]);
                O[n] = __builtin_amdgcn_mfma_f32_16x16x32_bf16(pa, vb, O[n], 0, 0, 0);
            }
        }

        if (t + 1 < 32) __syncthreads();  // gates reuse of buf[t&1]
    }

    // ---- epilogue: inv for row g*4+j fetched from its owner lane
    const int hh = pr >> 1, bb = pr & 1;
    float inv_own = 1.0f / l_run;
    #pragma unroll
    for (int j = 0; j < 4; ++j) {
        float inv = __shfl(inv_own, (lane & 48) | (g * 4 + j), 64);
        int s = qt * 128 + wave * 16 + g * 4 + j;
        float* op = out + (((size_t)(hh * S + s)) * 2 + bb) * 64;
        #pragma unroll
        for (int n = 0; n < 4; ++n) op[n * 16 + l15] = O[n][j] * inv;
    }
}

// ---------------- legacy fallback (round-6 verified kernel) for small ws_size
__global__ __launch_bounds__(256, 2) void attn_fwd(const float* __restrict__ x,
                                                   float* __restrict__ out) {
    __shared__ __align__(16) unsigned short Khi[KVB * D];
    __shared__ __align__(16) unsigned short Klo[KVB * D];
    __shared__ __align__(16) unsigned short Vt[D * KVB];
    __shared__ __align__(16) unsigned short Pl[4 * 16 * KVB];

    const int tid  = threadIdx.x;
    const int lane = tid & 63;
    const int wave = tid >> 6;
    const int l15  = lane & 15;
    const int g    = lane >> 4;
    const int pr = blockIdx.x & 31;
    const int qt = blockIdx.x >> 5;
    const float* __restrict__ base = x + (size_t)pr * (S * D);

    bf16x8 a_hi[2], a_lo[2];
    const int qrow = qt * 64 + wave * 16 + l15;
    #pragma unroll
    for (int c = 0; c < 2; ++c) {
        const float* qp = base + qrow * D + c * 32 + g * 8;
        float4 q0 = *(const float4*)(qp);
        float4 q1 = *(const float4*)(qp + 4);
        float qv[8] = {q0.x, q0.y, q0.z, q0.w, q1.x, q1.y, q1.z, q1.w};
        bf16x8 hv, lv;
        #pragma unroll
        for (int i = 0; i < 8; ++i) {
            unsigned short hb = f2bf(qv[i]);
            hv[i] = (short)hb;
            lv[i] = (short)f2bf(qv[i] - bf2f(hb));
        }
        a_hi[c] = hv;
        a_lo[c] = lv;
    }

    f32x4 O[4];
    f32x4 zero4 = {0.f, 0.f, 0.f, 0.f};
    #pragma unroll
    for (int n = 0; n < 4; ++n) O[n] = zero4;
    float m_run[4] = {-INFINITY, -INFINITY, -INFINITY, -INFINITY};
    float l_run[4] = {0.f, 0.f, 0.f, 0.f};

    for (int kv = 0; kv < S; kv += KVB) {
        #pragma unroll
        for (int it = 0; it < 4; ++it) {
            int o = it * 1024 + tid * 4;
            int r = o >> 6;
            int c = o & 63;
            float4 v = *(const float4*)(base + (size_t)(kv + r) * D + c);
            float vv[4] = {v.x, v.y, v.z, v.w};
            unsigned short hb[4];
            bf16x4 hvv, lvv;
            #pragma unroll
            for (int i = 0; i < 4; ++i) {
                hb[i] = f2bf(vv[i]);
                hvv[i] = (short)hb[i];
                lvv[i] = (short)f2bf(vv[i] - bf2f(hb[i]));
            }
            int idx = swz(r, c);
            *(bf16x4*)(&Khi[idx]) = hvv;
            *(bf16x4*)(&Klo[idx]) = lvv;
            #pragma unroll
            for (int i = 0; i < 4; ++i) Vt[swz(c + i, r)] = hb[i];
        }
        __syncthreads();

        f32x4 st[4];
        #pragma unroll
        for (int n = 0; n < 4; ++n) {
            f32x4 acc = zero4;
            #pragma unroll
            for (int c = 0; c < 2; ++c) {
                int krow = n * 16 + l15;
                int col = c * 32 + g * 8;
                bf16x8 bh = *(const bf16x8*)(&Khi[swz(krow, col)]);
                bf16x8 bl = *(const bf16x8*)(&Klo[swz(krow, col)]);
                acc = __builtin_amdgcn_mfma_f32_16x16x32_bf16(a_lo[c], bh, acc, 0, 0, 0);
                acc = __builtin_amdgcn_mfma_f32_16x16x32_bf16(a_hi[c], bl, acc, 0, 0, 0);
                acc = __builtin_amdgcn_mfma_f32_16x16x32_bf16(a_hi[c], bh, acc, 0, 0, 0);
            }
            st[n] = acc;
        }

        #pragma unroll
        for (int j = 0; j < 4; ++j) {
            float tt[4];
            #pragma unroll
            for (int n = 0; n < 4; ++n) tt[n] = st[n][j] * SCALE;
            float mx = fmaxf(fmaxf(tt[0], tt[1]), fmaxf(tt[2], tt[3]));
            #pragma unroll
            for (int w = 1; w <= 8; w <<= 1) mx = fmaxf(mx, __shfl_xor(mx, w, 64));
            float M = fmaxf(m_run[j], mx);
            float f = exp2f((m_run[j] - M) * LOG2E);
            m_run[j] = M;
            float p[4], sum = 0.f;
            #pragma unroll
            for (int n = 0; n < 4; ++n) {
                p[n] = exp2f((tt[n] - M) * LOG2E);
                sum += p[n];
            }
            #pragma unroll
            for (int w = 1; w <= 8; w <<= 1) sum += __shfl_xor(sum, w, 64);
            l_run[j] = l_run[j] * f + sum;
            #pragma unroll
            for (int n = 0; n < 4; ++n) O[n][j] *= f;
            int r = g * 4 + j;
            #pragma unroll
            for (int n = 0; n < 4; ++n)
                Pl[wave * 1024 + r * 64 + ((n * 16 + l15) ^ ((r & 7) << 3))] = f2bf(p[n]);
        }
        __syncthreads();

        #pragma unroll
        for (int c = 0; c < 2; ++c) {
            int pcol = c * 32 + g * 8;
            bf16x8 pa = *(const bf16x8*)(&Pl[wave * 1024 + swz(l15, pcol)]);
            #pragma unroll
            for (int n = 0; n < 4; ++n) {
                bf16x8 vb = *(const bf16x8*)(&Vt[swz(n * 16 + l15, pcol)]);
                O[n] = __builtin_amdgcn_mfma_f32_16x16x32_bf16(pa, vb, O[n], 0, 0, 0);
            }
        }
        __syncthreads();
    }

    const int hh = pr >> 1, bb = pr & 1;
    #pragma unroll
    for (int j = 0; j < 4; ++j) {
        float inv = 1.0f / l_run[j];
        int s = qt * 64 + wave * 16 + g * 4 + j;
        float* op = out + (((size_t)(hh * S + s)) * 2 + bb) * 64;
        #pragma unroll
        for (int n = 0; n < 4; ++n) op[n * 16 + l15] = O[n][j] * inv;
    }
}

extern "C" void kernel_launch(void* const* d_in, const int* in_sizes, int n_in,
                              void* d_out, int out_size, void* d_ws, size_t ws_size,
                              hipStream_t stream) {
    (void)in_sizes; (void)n_in; (void)out_size;
    const float* x = (const float*)d_in[0];
    float* out = (float*)d_out;
    if (ws_size >= WS_NEED) {
        unsigned short* Khi_g = (unsigned short*)d_ws;
        unsigned short* Vt_g  = Khi_g + ARR;
        prep_convert<<<dim3(1024), dim3(256), 0, stream>>>(x, Khi_g, Vt_g);
        attn_fwd2<<<dim3(512), dim3(512), 0, stream>>>(Khi_g, Vt_g, out);
    } else {
        attn_fwd<<<dim3(1024), dim3(256), 0, stream>>>(x, out);
    }
}